// Round 13
// baseline (375.322 us; speedup 1.0000x reference)
//
#include <hip/hip_runtime.h>
#include <cmath>

typedef __attribute__((ext_vector_type(8))) short bf16x8;
typedef __attribute__((ext_vector_type(4))) float f32x4;
typedef __attribute__((ext_vector_type(16))) float f32x16;
typedef unsigned short u16;

__device__ __forceinline__ u16 f2bf(float f) {
  union { float f; unsigned u; } x; x.f = f;
  return (u16)((x.u + 0x7FFFu + ((x.u >> 16) & 1u)) >> 16);
}

__device__ __forceinline__ unsigned cvtpk(float lo, float hi) {
  unsigned r;
  asm("v_cvt_pk_bf16_f32 %0, %1, %2" : "=v"(r) : "v"(lo), "v"(hi));
  return r;
}

__device__ __forceinline__ void gload_lds16(const void* g, void* l) {
  __builtin_amdgcn_global_load_lds((const __attribute__((address_space(1))) unsigned*)g,
                                   (__attribute__((address_space(3))) unsigned*)l,
                                   16, 0, 0);
}

// One fused cast: dst segments are contiguous in ws:
// [x 16777216 | wq 4194304 | wk 1048576 | wv 1048576 | wo 4194304]
__global__ __launch_bounds__(256) void cast_all_kernel(const float* __restrict__ x,
                                                       const float* __restrict__ wq,
                                                       const float* __restrict__ wk,
                                                       const float* __restrict__ wv,
                                                       const float* __restrict__ wo,
                                                       u16* __restrict__ out) {
  const long b1 = 16777216, b2 = 20971520, b3 = 22020096, b4 = 23068672, b5 = 27262976;
  long i = (long)blockIdx.x * blockDim.x + threadIdx.x;
  long stride = (long)gridDim.x * blockDim.x;
  for (long j = i * 4; j < b5; j += stride * 4) {
    const float* src; long off;
    if (j < b1)      { src = x;  off = j; }
    else if (j < b2) { src = wq; off = j - b1; }
    else if (j < b3) { src = wk; off = j - b2; }
    else if (j < b4) { src = wv; off = j - b3; }
    else             { src = wo; off = j - b4; }
    float4 v = *(const float4*)(src + off);
    ushort4 o;
    o.x = f2bf(v.x); o.y = f2bf(v.y); o.z = f2bf(v.z); o.w = f2bf(v.w);
    *(ushort4*)(out + j) = o;
  }
}

// ---------------- 256x256 counted-vmcnt deep-pipeline GEMM ----------------
// EPI 1: merged QKV epilogue. B = [Wq; Wk; Wv] (3072x2048 contiguous). Per 256-col block:
//   n0 <  2048: Q + RoPE*qscale -> outp (B,16,T,128)
//   n0 <  2560: K + RoPE        -> kp   (B, 4,T,128)
//   else:       V               -> vtp  (B, 4,128,T)  (transposed)
// EPI 2: plain f32 write to [M, N].
template <int EPI>
__global__ __launch_bounds__(512, 2) void gemm_bt256(const u16* __restrict__ A,
                                                     const u16* __restrict__ B,
                                                     void* __restrict__ outp,
                                                     u16* __restrict__ kp,
                                                     u16* __restrict__ vtp,
                                                     int M, int N, int K,
                                                     const float* __restrict__ cosp,
                                                     const float* __restrict__ sinp,
                                                     float scale) {
  __shared__ u16 lds[65536];   // [buf][A 256x64 | B 256x64], 128KB
  const int tid = threadIdx.x;
  const int lane = tid & 63;
  const int l16 = lane & 15, lhi = lane >> 4;
  const int w = tid >> 6;
  const int wr = w >> 2, wc = w & 3;
  const int m0 = blockIdx.y * 256;
  const int n0 = blockIdx.x * 256;

  f32x4 acc[8][4];
#pragma unroll
  for (int i = 0; i < 8; ++i)
#pragma unroll
    for (int j = 0; j < 4; ++j) acc[i][j] = (f32x4)0.0f;

  const int NT = K >> 6;

  auto stage = [&](int t, int buf) {
    const int k0 = t << 6;
    u16* Ad = lds + buf * 32768;
    u16* Bd = Ad + 16384;
#pragma unroll
    for (int j = 0; j < 4; ++j) {
      int c = tid + j * 512;
      int row = c >> 3;
      int sboff = ((c & 7) * 16) ^ ((row & 7) << 4);
      gload_lds16(A + (size_t)(m0 + row) * K + k0 + (sboff >> 1), Ad + (size_t)c * 8);
    }
#pragma unroll
    for (int j = 0; j < 4; ++j) {
      int c = tid + j * 512;
      int row = c >> 3;
      int sboff = ((c & 7) * 16) ^ ((row & 7) << 4);
      gload_lds16(B + (size_t)(n0 + row) * K + k0 + (sboff >> 1), Bd + (size_t)c * 8);
    }
  };

  stage(0, 0);
  stage(1, 1);

  for (int t = 0; t < NT; ++t) {
    const int cur = t & 1;
    if (t + 1 < NT) { asm volatile("s_waitcnt vmcnt(8)" ::: "memory"); }
    else            { asm volatile("s_waitcnt vmcnt(0)" ::: "memory"); }
    __builtin_amdgcn_s_barrier();
    const char* Ab = (const char*)(lds + cur * 32768);
    const char* Bb = (const char*)(lds + cur * 32768 + 16384);
#pragma unroll
    for (int qm = 0; qm < 2; ++qm)
#pragma unroll
      for (int qn = 0; qn < 2; ++qn) {
        bf16x8 af[4][2], bfr[2][2];
#pragma unroll
        for (int mi = 0; mi < 4; ++mi) {
          int ra = wr * 128 + qm * 64 + mi * 16 + l16;
#pragma unroll
          for (int kk = 0; kk < 2; ++kk)
            af[mi][kk] = *(const bf16x8*)(Ab + ra * 128 + ((kk * 64 + lhi * 16) ^ ((ra & 7) << 4)));
        }
#pragma unroll
        for (int ni = 0; ni < 2; ++ni) {
          int rb = wc * 64 + qn * 32 + ni * 16 + l16;
#pragma unroll
          for (int kk = 0; kk < 2; ++kk)
            bfr[ni][kk] = *(const bf16x8*)(Bb + rb * 128 + ((kk * 64 + lhi * 16) ^ ((rb & 7) << 4)));
        }
        __builtin_amdgcn_s_setprio(1);
#pragma unroll
        for (int kk = 0; kk < 2; ++kk)
#pragma unroll
          for (int mi = 0; mi < 4; ++mi)
#pragma unroll
            for (int ni = 0; ni < 2; ++ni)
              acc[qm * 4 + mi][qn * 2 + ni] = __builtin_amdgcn_mfma_f32_16x16x32_bf16(
                  af[mi][kk], bfr[ni][kk], acc[qm * 4 + mi][qn * 2 + ni], 0, 0, 0);
        __builtin_amdgcn_s_setprio(0);
      }
    asm volatile("s_waitcnt lgkmcnt(0)" ::: "memory");
    __builtin_amdgcn_s_barrier();
    if (t + 2 < NT) stage(t + 2, cur);
  }

  if (EPI == 2) {
    float* o = (float*)outp;
#pragma unroll
    for (int mi8 = 0; mi8 < 8; ++mi8)
#pragma unroll
      for (int r = 0; r < 4; ++r) {
        int row = m0 + wr * 128 + mi8 * 16 + lhi * 4 + r;
#pragma unroll
        for (int nj = 0; nj < 4; ++nj) {
          int col = n0 + wc * 64 + nj * 16 + l16;
          o[(size_t)row * N + col] = acc[mi8][nj][r];
        }
      }
  } else {  // EPI == 1: merged QKV
    u16* oq = (u16*)outp;
#pragma unroll
    for (int mi8 = 0; mi8 < 8; ++mi8)
#pragma unroll
      for (int r = 0; r < 4; ++r) {
        int row = m0 + wr * 128 + mi8 * 16 + lhi * 4 + r;
        int b = row >> 11;
        int tt = row & 2047;
#pragma unroll
        for (int nj = 0; nj < 4; ++nj) {
          int col = n0 + wc * 64 + nj * 16 + l16;
          float v = acc[mi8][nj][r];
          if (n0 < 2048) {          // Q: RoPE + qscale
            int dd = col & 127;
            float p = __shfl_xor(v, 1);
            float c = cosp[tt * 64 + (dd >> 1)];
            float s = sinp[tt * 64 + (dd >> 1)];
            v = (lane & 1) ? fmaf(p, s, v * c) : fmaf(v, c, -p * s);
            v *= scale;
            oq[((size_t)(b * 16 + (col >> 7)) * 2048 + tt) * 128 + dd] = f2bf(v);
          } else if (n0 < 2560) {   // K: RoPE
            int c2 = col - 2048;
            int dd = c2 & 127;
            float p = __shfl_xor(v, 1);
            float c = cosp[tt * 64 + (dd >> 1)];
            float s = sinp[tt * 64 + (dd >> 1)];
            v = (lane & 1) ? fmaf(p, s, v * c) : fmaf(v, c, -p * s);
            kp[((size_t)(b * 4 + (c2 >> 7)) * 2048 + tt) * 128 + dd] = f2bf(v);
          } else {                  // V: write transposed (b, kvh, d, t)
            int c2 = col - 2560;
            vtp[((size_t)(b * 4 + (c2 >> 7)) * 128 + (c2 & 127)) * 2048 + tt] = f2bf(v);
          }
        }
      }
  }
}

// ---------------- Flash attention: 32x32 swapped-QK^T + K/V double-buffer ----------------
// (byte-identical to round 12: LPT qt map, permlane32_swap P-redistribute, setprio MFMA)
__global__ __launch_bounds__(512, 2) void attn_kernel(const u16* __restrict__ Q,
                                                      const u16* __restrict__ Kp,
                                                      const u16* __restrict__ Vtp,
                                                      u16* __restrict__ O) {
  __shared__ u16 lds[32768];          // 64KB: Kbuf0 | Kbuf1 | Vbuf0 | Vbuf1 (8192 u16 each)

  const int tid = threadIdx.x;
  const int lane = tid & 63;
  const int w = tid >> 6;             // 0..7
  const int l5 = lane & 31, hi = lane >> 5;
  const int bid = blockIdx.x;
  const int qt = 7 - (bid >> 6);      // LPT: heavy q-tiles first
  const int hb = bid & 63;
  const int h = hb >> 2;
  const int b = hb & 3;
  const int kvh = h >> 2;
  const int q0 = qt * 256;
  const int wbase = tid - lane;
  const int wrow0 = q0 + w * 32;      // this wave's first q row
  const int qg = wrow0 + l5;          // this lane's q row

  const u16* Qb = Q + ((size_t)((b * 16 + h) * 2048 + wrow0)) * 128;
  const u16* Kb = Kp + (size_t)(b * 4 + kvh) * 2048 * 128;
  const u16* Vtb = Vtp + (size_t)(b * 4 + kvh) * 128 * 2048;

  bf16x8 qf[8];
#pragma unroll
  for (int ks = 0; ks < 8; ++ks)
    qf[ks] = *(const bf16x8*)(Qb + (size_t)l5 * 128 + ks * 16 + hi * 8);

  f32x16 oacc[4];
#pragma unroll
  for (int i = 0; i < 4; ++i) oacc[i] = (f32x16)0.0f;
  float m = -3.0e38f, l = 0.0f;

  const int nkt = 4 * qt + 4;

  auto stageKV = [&](int kt, int buf) {
    const int t0k = kt * 64;
    u16* Kd = lds + buf * 8192;
    u16* Vd = lds + 16384 + buf * 8192;
#pragma unroll
    for (int j = 0; j < 2; ++j) {
      int c = tid + j * 512;
      int row = c >> 4;
      int sboff = ((c & 15) * 16) ^ ((row & 15) << 4);
      gload_lds16(Kb + (size_t)(t0k + row) * 128 + (sboff >> 1),
                  Kd + (size_t)(wbase + j * 512) * 8);
    }
#pragma unroll
    for (int j = 0; j < 2; ++j) {
      int c = tid + j * 512;
      int d = c >> 3;
      int sboff = ((c & 7) * 16) ^ ((d & 7) << 4);
      gload_lds16(Vtb + (size_t)d * 2048 + t0k + (sboff >> 1),
                  Vd + (size_t)(wbase + j * 512) * 8);
    }
  };

  stageKV(0, 0);

  for (int kt = 0; kt < nkt; ++kt) {
    const int t0 = kt * 64;
    const int cur = kt & 1;
    if (kt + 1 < nkt) {
      stageKV(kt + 1, cur ^ 1);
      asm volatile("s_waitcnt vmcnt(4)" ::: "memory");
    } else {
      asm volatile("s_waitcnt vmcnt(0)" ::: "memory");
    }
    __builtin_amdgcn_s_barrier();      // buf[cur] staged by all waves

    if (t0 <= wrow0 + 31) {
      const char* ksb = (const char*)(lds + cur * 8192);
      const char* vtb = (const char*)(lds + 16384 + cur * 8192);

      // S^T = mfma(K, Q): p[kt2*16+r] = S[kv][q], kv = kt2*32 + (r&3)+8*(r>>2)+4*hi
      float p[32];
#pragma unroll
      for (int kt2 = 0; kt2 < 2; ++kt2) {
        f32x16 sacc = (f32x16)0.0f;
        int row = kt2 * 32 + l5;
        __builtin_amdgcn_s_setprio(1);
#pragma unroll
        for (int ks = 0; ks < 8; ++ks) {
          bf16x8 kf = *(const bf16x8*)(ksb + row * 256 + ((ks * 32 + hi * 16) ^ ((row & 15) << 4)));
          sacc = __builtin_amdgcn_mfma_f32_32x32x16_bf16(kf, qf[ks], sacc, 0, 0, 0);
        }
        __builtin_amdgcn_s_setprio(0);
#pragma unroll
        for (int r = 0; r < 16; ++r) p[kt2 * 16 + r] = sacc[r];
      }

      if (t0 + 63 > wrow0) {  // straddles diagonal: causal mask
#pragma unroll
        for (int kt2 = 0; kt2 < 2; ++kt2)
#pragma unroll
          for (int r = 0; r < 16; ++r) {
            int kvg = t0 + kt2 * 32 + (r & 3) + 8 * (r >> 2) + 4 * hi;
            if (kvg > qg) p[kt2 * 16 + r] = -3.0e38f;
          }
      }

      // in-lane row max + cross-half combine
      float mx[16];
#pragma unroll
      for (int i = 0; i < 16; ++i) mx[i] = fmaxf(p[i], p[i + 16]);
#pragma unroll
      for (int i = 0; i < 8; ++i) mx[i] = fmaxf(mx[i], mx[i + 8]);
#pragma unroll
      for (int i = 0; i < 4; ++i) mx[i] = fmaxf(mx[i], mx[i + 4]);
      float rm = fmaxf(fmaxf(mx[0], mx[1]), fmaxf(mx[2], mx[3]));
      rm = fmaxf(rm, __shfl_xor(rm, 32));

      bool defer = __all(rm <= m + 8.0f);
      if (!defer) {
        float mnew = fmaxf(m, rm);
        float sc = exp2f(m - mnew);
        m = mnew;
        l *= sc;
#pragma unroll
        for (int i = 0; i < 4; ++i)
#pragma unroll
          for (int r = 0; r < 16; ++r) oacc[i][r] *= sc;
      }

      // p = exp2(S - m); in-lane sum
#pragma unroll
      for (int i = 0; i < 32; ++i) p[i] = exp2f(p[i] - m);
      float sm[16];
#pragma unroll
      for (int i = 0; i < 16; ++i) sm[i] = p[i] + p[i + 16];
#pragma unroll
      for (int i = 0; i < 8; ++i) sm[i] += sm[i + 8];
#pragma unroll
      for (int i = 0; i < 4; ++i) sm[i] += sm[i + 4];
      float s2 = (sm[0] + sm[1]) + (sm[2] + sm[3]);
      s2 += __shfl_xor(s2, 32);
      l += s2;

      // P pack + permlane32_swap redistribute + PV: O^T += mfma(A=V^T, B=P)
#pragma unroll
      for (int kt2 = 0; kt2 < 2; ++kt2) {
#pragma unroll
        for (int sl = 0; sl < 2; ++sl) {
          int base = kt2 * 16 + sl * 8;
          unsigned A0 = cvtpk(p[base + 0], p[base + 1]);
          unsigned A1 = cvtpk(p[base + 2], p[base + 3]);
          unsigned A2 = cvtpk(p[base + 4], p[base + 5]);
          unsigned A3 = cvtpk(p[base + 6], p[base + 7]);
          asm volatile("v_permlane32_swap_b32 %0, %1" : "+v"(A0), "+v"(A2));
          asm volatile("v_permlane32_swap_b32 %0, %1" : "+v"(A1), "+v"(A3));
          union { unsigned u[4]; bf16x8 v; } pf;
          pf.u[0] = A0;
          pf.u[1] = A1;
          pf.u[2] = A2;
          pf.u[3] = A3;
          int s = kt2 * 2 + sl;
          __builtin_amdgcn_s_setprio(1);
#pragma unroll
          for (int dt = 0; dt < 4; ++dt) {
            int row = dt * 32 + l5;
            bf16x8 vb = *(const bf16x8*)(vtb + row * 128 + ((s * 32 + hi * 16) ^ ((row & 7) << 4)));
            oacc[dt] = __builtin_amdgcn_mfma_f32_32x32x16_bf16(vb, pf.v, oacc[dt], 0, 0, 0);
          }
          __builtin_amdgcn_s_setprio(0);
        }
      }
    }

    asm volatile("s_waitcnt lgkmcnt(0)" ::: "memory");
    __builtin_amdgcn_s_barrier();      // all waves done reading buf[cur]
  }

  // normalize in-lane; two half-passes through OS overlay (waves 0-3, then 4-7)
  float inv = 1.0f / l;
  __syncthreads();
  for (int half = 0; half < 2; ++half) {
    if ((w >> 2) == half) {
      u16* OSw = lds + (w & 3) * 4352;     // [32 q][136] padded
#pragma unroll
      for (int dt = 0; dt < 4; ++dt)
#pragma unroll
        for (int r = 0; r < 16; ++r) {
          int d = dt * 32 + (r & 3) + 8 * (r >> 2) + 4 * hi;
          OSw[l5 * 136 + d] = f2bf(oacc[dt][r] * inv);
        }
    }
    __syncthreads();
    u16* Ob = O + ((size_t)(b * 2048 + q0 + half * 128)) * 2048 + h * 128;
#pragma unroll
    for (int j = 0; j < 4; ++j) {
      int c = tid + j * 512;
      int row = c >> 4, col = c & 15;
      *(bf16x8*)(Ob + (size_t)row * 2048 + col * 8) =
          *(const bf16x8*)&lds[(row >> 5) * 4352 + (row & 31) * 136 + col * 8];
    }
    __syncthreads();
  }
}

extern "C" void kernel_launch(void* const* d_in, const int* in_sizes, int n_in,
                              void* d_out, int out_size, void* d_ws, size_t ws_size,
                              hipStream_t stream) {
  (void)in_sizes; (void)n_in; (void)out_size; (void)ws_size;
  const float* x    = (const float*)d_in[0];
  const float* Wq   = (const float*)d_in[1];
  const float* Wk   = (const float*)d_in[2];
  const float* Wv   = (const float*)d_in[3];
  const float* Wo   = (const float*)d_in[4];
  const float* cosp = (const float*)d_in[5];
  const float* sinp = (const float*)d_in[6];

  u16* ws  = (u16*)d_ws;
  u16* xbf = ws;               // 16,777,216 elems (B*T x C)  -- reused as attn out
  u16* Wqb = xbf + 16777216;   //  4,194,304  } contiguous 3072x2048 QKV weight
  u16* Wkb = Wqb + 4194304;    //  1,048,576  }
  u16* Wvb = Wkb + 1048576;    //  1,048,576  }
  u16* Wob = Wvb + 1048576;    //  4,194,304
  u16* Qb  = Wob + 4194304;    // 16,777,216 (B,H,T,D)
  u16* Kb  = Qb + 16777216;    //  4,194,304 (B,HKV,T,D)
  u16* Vb  = Kb + 4194304;     //  4,194,304 (B,HKV,D,T)  == V^T
  u16* AO  = xbf;              // attention output (B,T,C), reuses x region

  cast_all_kernel<<<2048, 256, 0, stream>>>(x, Wq, Wk, Wv, Wo, ws);

  const float qscale = (float)(1.4426950408889634 / sqrt(128.0));

  // Merged QKV projection: B = [Wq; Wk; Wv] contiguous, N = 3072, 384 blocks (co-resident)
  gemm_bt256<1><<<dim3(12, 32), 512, 0, stream>>>(xbf, Wqb, Qb, Kb, Vb,
                                                  8192, 3072, 2048, cosp, sinp, qscale);

  attn_kernel<<<512, 512, 0, stream>>>(Qb, Kb, Vb, AO);

  gemm_bt256<2><<<dim3(8, 32), 512, 0, stream>>>(AO, Wob, d_out, nullptr, nullptr,
                                                 8192, 2048, 2048, nullptr, nullptr, 1.0f);
}

// Round 14
// 325.486 us; speedup vs baseline: 1.1531x; 1.1531x over previous
//
#include <hip/hip_runtime.h>
#include <cmath>

typedef __attribute__((ext_vector_type(8))) short bf16x8;
typedef __attribute__((ext_vector_type(4))) float f32x4;
typedef __attribute__((ext_vector_type(16))) float f32x16;
typedef unsigned short u16;

__device__ __forceinline__ u16 f2bf(float f) {
  union { float f; unsigned u; } x; x.f = f;
  return (u16)((x.u + 0x7FFFu + ((x.u >> 16) & 1u)) >> 16);
}

__device__ __forceinline__ unsigned cvtpk(float lo, float hi) {
  unsigned r;
  asm("v_cvt_pk_bf16_f32 %0, %1, %2" : "=v"(r) : "v"(lo), "v"(hi));
  return r;
}

__device__ __forceinline__ void gload_lds16(const void* g, void* l) {
  __builtin_amdgcn_global_load_lds((const __attribute__((address_space(1))) unsigned*)g,
                                   (__attribute__((address_space(3))) unsigned*)l,
                                   16, 0, 0);
}

// One fused cast: dst segments are contiguous in ws:
// [x 16777216 | wq 4194304 | wk 1048576 | wv 1048576 | wo 4194304]
__global__ __launch_bounds__(256) void cast_all_kernel(const float* __restrict__ x,
                                                       const float* __restrict__ wq,
                                                       const float* __restrict__ wk,
                                                       const float* __restrict__ wv,
                                                       const float* __restrict__ wo,
                                                       u16* __restrict__ out) {
  const long b1 = 16777216, b2 = 20971520, b3 = 22020096, b4 = 23068672, b5 = 27262976;
  long i = (long)blockIdx.x * blockDim.x + threadIdx.x;
  long stride = (long)gridDim.x * blockDim.x;
  for (long j = i * 4; j < b5; j += stride * 4) {
    const float* src; long off;
    if (j < b1)      { src = x;  off = j; }
    else if (j < b2) { src = wq; off = j - b1; }
    else if (j < b3) { src = wk; off = j - b2; }
    else if (j < b4) { src = wv; off = j - b3; }
    else             { src = wo; off = j - b4; }
    float4 v = *(const float4*)(src + off);
    ushort4 o;
    o.x = f2bf(v.x); o.y = f2bf(v.y); o.z = f2bf(v.z); o.w = f2bf(v.w);
    *(ushort4*)(out + j) = o;
  }
}

// ---------------- 256x256 counted-vmcnt deep-pipeline GEMM (round-12 form) ----------------
// EPI 0: RoPE + scale, bf16 to (b, h=col>>7, t, d=col&127). EPI 2: f32 [M,N].
template <int EPI>
__global__ __launch_bounds__(512, 2) void gemm_bt256(const u16* __restrict__ A,
                                                     const u16* __restrict__ B,
                                                     void* __restrict__ outp,
                                                     int M, int N, int K,
                                                     const float* __restrict__ cosp,
                                                     const float* __restrict__ sinp,
                                                     float scale) {
  __shared__ u16 lds[65536];   // [buf][A 256x64 | B 256x64], 128KB
  const int tid = threadIdx.x;
  const int lane = tid & 63;
  const int l16 = lane & 15, lhi = lane >> 4;
  const int w = tid >> 6;
  const int wr = w >> 2, wc = w & 3;
  const int m0 = blockIdx.y * 256;
  const int n0 = blockIdx.x * 256;

  f32x4 acc[8][4];
#pragma unroll
  for (int i = 0; i < 8; ++i)
#pragma unroll
    for (int j = 0; j < 4; ++j) acc[i][j] = (f32x4)0.0f;

  const int NT = K >> 6;

  auto stage = [&](int t, int buf) {
    const int k0 = t << 6;
    u16* Ad = lds + buf * 32768;
    u16* Bd = Ad + 16384;
#pragma unroll
    for (int j = 0; j < 4; ++j) {
      int c = tid + j * 512;
      int row = c >> 3;
      int sboff = ((c & 7) * 16) ^ ((row & 7) << 4);
      gload_lds16(A + (size_t)(m0 + row) * K + k0 + (sboff >> 1), Ad + (size_t)c * 8);
    }
#pragma unroll
    for (int j = 0; j < 4; ++j) {
      int c = tid + j * 512;
      int row = c >> 3;
      int sboff = ((c & 7) * 16) ^ ((row & 7) << 4);
      gload_lds16(B + (size_t)(n0 + row) * K + k0 + (sboff >> 1), Bd + (size_t)c * 8);
    }
  };

  stage(0, 0);
  stage(1, 1);

  for (int t = 0; t < NT; ++t) {
    const int cur = t & 1;
    if (t + 1 < NT) { asm volatile("s_waitcnt vmcnt(8)" ::: "memory"); }
    else            { asm volatile("s_waitcnt vmcnt(0)" ::: "memory"); }
    __builtin_amdgcn_s_barrier();
    const char* Ab = (const char*)(lds + cur * 32768);
    const char* Bb = (const char*)(lds + cur * 32768 + 16384);
#pragma unroll
    for (int qm = 0; qm < 2; ++qm)
#pragma unroll
      for (int qn = 0; qn < 2; ++qn) {
        bf16x8 af[4][2], bfr[2][2];
#pragma unroll
        for (int mi = 0; mi < 4; ++mi) {
          int ra = wr * 128 + qm * 64 + mi * 16 + l16;
#pragma unroll
          for (int kk = 0; kk < 2; ++kk)
            af[mi][kk] = *(const bf16x8*)(Ab + ra * 128 + ((kk * 64 + lhi * 16) ^ ((ra & 7) << 4)));
        }
#pragma unroll
        for (int ni = 0; ni < 2; ++ni) {
          int rb = wc * 64 + qn * 32 + ni * 16 + l16;
#pragma unroll
          for (int kk = 0; kk < 2; ++kk)
            bfr[ni][kk] = *(const bf16x8*)(Bb + rb * 128 + ((kk * 64 + lhi * 16) ^ ((rb & 7) << 4)));
        }
        __builtin_amdgcn_s_setprio(1);
#pragma unroll
        for (int kk = 0; kk < 2; ++kk)
#pragma unroll
          for (int mi = 0; mi < 4; ++mi)
#pragma unroll
            for (int ni = 0; ni < 2; ++ni)
              acc[qm * 4 + mi][qn * 2 + ni] = __builtin_amdgcn_mfma_f32_16x16x32_bf16(
                  af[mi][kk], bfr[ni][kk], acc[qm * 4 + mi][qn * 2 + ni], 0, 0, 0);
        __builtin_amdgcn_s_setprio(0);
      }
    asm volatile("s_waitcnt lgkmcnt(0)" ::: "memory");
    __builtin_amdgcn_s_barrier();
    if (t + 2 < NT) stage(t + 2, cur);
  }

  if (EPI == 2) {
    float* o = (float*)outp;
#pragma unroll
    for (int mi8 = 0; mi8 < 8; ++mi8)
#pragma unroll
      for (int r = 0; r < 4; ++r) {
        int row = m0 + wr * 128 + mi8 * 16 + lhi * 4 + r;
#pragma unroll
        for (int nj = 0; nj < 4; ++nj) {
          int col = n0 + wc * 64 + nj * 16 + l16;
          o[(size_t)row * N + col] = acc[mi8][nj][r];
        }
      }
  } else {
    u16* o = (u16*)outp;
    const int nheads = N >> 7;
#pragma unroll
    for (int mi8 = 0; mi8 < 8; ++mi8)
#pragma unroll
      for (int r = 0; r < 4; ++r) {
        int row = m0 + wr * 128 + mi8 * 16 + lhi * 4 + r;
        int b = row >> 11;
        int tt = row & 2047;
#pragma unroll
        for (int nj = 0; nj < 4; ++nj) {
          int col = n0 + wc * 64 + nj * 16 + l16;
          int hh = col >> 7, dd = col & 127;
          float v = acc[mi8][nj][r];
          float p = __shfl_xor(v, 1);
          float c = cosp[tt * 64 + (dd >> 1)];
          float s = sinp[tt * 64 + (dd >> 1)];
          v = (lane & 1) ? fmaf(p, s, v * c) : fmaf(v, c, -p * s);
          v *= scale;
          o[((size_t)(b * nheads + hh) * 2048 + tt) * 128 + dd] = f2bf(v);
        }
      }
  }
}

// ---------------- 128x128 2-phase GEMM (KV projection only, round-12 form) ----------------
template <int EPI>
__global__ __launch_bounds__(256) void gemm_bt(const u16* __restrict__ A,
                                               const u16* __restrict__ B,
                                               void* __restrict__ outp,
                                               u16* __restrict__ vtp,
                                               int M, int N, int K,
                                               const float* __restrict__ cosp,
                                               const float* __restrict__ sinp,
                                               float scale) {
  __shared__ u16 As[128 * 64];
  __shared__ u16 Bs[128 * 64];
  const int tid = threadIdx.x;
  const int lane = tid & 63;
  const int l16 = lane & 15, lhi = lane >> 4;
  const int w = tid >> 6;
  const int wr = w >> 1, wc = w & 1;
  const int m0 = blockIdx.y * 128;
  const int n0 = blockIdx.x * 128;
  const int wbase = tid - lane;

  f32x4 acc[4][4];
#pragma unroll
  for (int i = 0; i < 4; ++i)
#pragma unroll
    for (int j = 0; j < 4; ++j) acc[i][j] = (f32x4)0.0f;

  for (int k0 = 0; k0 < K; k0 += 64) {
    __syncthreads();
#pragma unroll
    for (int j = 0; j < 4; ++j) {
      int c = tid + j * 256;
      gload_lds16(A + (size_t)(m0 + (c >> 3)) * K + k0 + (c & 7) * 8,
                  As + (size_t)(wbase + j * 256) * 8);
    }
#pragma unroll
    for (int j = 0; j < 4; ++j) {
      int c = tid + j * 256;
      gload_lds16(B + (size_t)(n0 + (c >> 3)) * K + k0 + (c & 7) * 8,
                  Bs + (size_t)(wbase + j * 256) * 8);
    }
    __syncthreads();
#pragma unroll
    for (int kk = 0; kk < 64; kk += 32) {
      bf16x8 af[4], bfr[4];
#pragma unroll
      for (int mi = 0; mi < 4; ++mi)
        af[mi] = *(const bf16x8*)&As[(wr * 64 + mi * 16 + l16) * 64 + kk + lhi * 8];
#pragma unroll
      for (int ni = 0; ni < 4; ++ni)
        bfr[ni] = *(const bf16x8*)&Bs[(wc * 64 + ni * 16 + l16) * 64 + kk + lhi * 8];
#pragma unroll
      for (int mi = 0; mi < 4; ++mi)
#pragma unroll
        for (int ni = 0; ni < 4; ++ni)
          acc[mi][ni] = __builtin_amdgcn_mfma_f32_16x16x32_bf16(af[mi], bfr[ni], acc[mi][ni], 0, 0, 0);
    }
  }

  {  // EPI == 3 (merged KV)
    const int bx = blockIdx.x;
    if (bx < 4) {
      u16* o = (u16*)outp;
#pragma unroll
      for (int mi = 0; mi < 4; ++mi)
#pragma unroll
        for (int r = 0; r < 4; ++r) {
          int row = m0 + wr * 64 + mi * 16 + lhi * 4 + r;
          int b = row >> 11;
          int t = row & 2047;
          size_t base = ((size_t)(b * 4 + bx) * 2048 + t) * 128;
#pragma unroll
          for (int ni = 0; ni < 4; ++ni) {
            int d = wc * 64 + ni * 16 + l16;
            float v = acc[mi][ni][r];
            float p = __shfl_xor(v, 1);
            float c = cosp[t * 64 + (d >> 1)];
            float s = sinp[t * 64 + (d >> 1)];
            v = (lane & 1) ? fmaf(p, s, v * c) : fmaf(v, c, -p * s);
            o[base + d] = f2bf(v);
          }
        }
    } else {
      const int kvh = bx - 4;
#pragma unroll
      for (int mi = 0; mi < 4; ++mi)
#pragma unroll
        for (int r = 0; r < 4; ++r) {
          int row = m0 + wr * 64 + mi * 16 + lhi * 4 + r;
          int b = row >> 11;
          int t = row & 2047;
          size_t base = ((size_t)(b * 4 + kvh) * 128) * 2048 + t;
#pragma unroll
          for (int ni = 0; ni < 4; ++ni) {
            int d = wc * 64 + ni * 16 + l16;
            vtp[base + (size_t)d * 2048] = f2bf(acc[mi][ni][r]);
          }
        }
    }
  }
}

// ---------------- Flash attention: uniform-work paired q-tiles ----------------
// Grid 256 = 64 (h,b) x 4 pairs; block = 8 waves x 32 q-rows, 256-row q-tile.
// Each block processes q-tiles pa and 7-pa sequentially: (4*pa+4)+(4*(7-pa)+4) = 36
// kt-iters for EVERY block -- perfect balance regardless of workgroup->CU assignment
// (round 11 showed assignment is undefined and unsteerable). kt-loop body, staging,
// and epilogue are byte-identical to the round-12-verified kernel.
__global__ __launch_bounds__(512, 2) void attn_kernel(const u16* __restrict__ Q,
                                                      const u16* __restrict__ Kp,
                                                      const u16* __restrict__ Vtp,
                                                      u16* __restrict__ O) {
  __shared__ u16 lds[32768];          // 64KB: Kbuf0 | Kbuf1 | Vbuf0 | Vbuf1 (8192 u16 each)

  const int tid = threadIdx.x;
  const int lane = tid & 63;
  const int w = tid >> 6;             // 0..7
  const int l5 = lane & 31, hi = lane >> 5;
  const int bid = blockIdx.x;
  const int hb = bid & 63;
  const int pa = bid >> 6;            // 0..3: q-tile pair (pa, 7-pa)
  const int h = hb >> 2;
  const int b = hb & 3;
  const int kvh = h >> 2;
  const int wbase = tid - lane;

  const u16* Kb = Kp + (size_t)(b * 4 + kvh) * 2048 * 128;
  const u16* Vtb = Vtp + (size_t)(b * 4 + kvh) * 128 * 2048;

  auto stageKV = [&](int kt, int buf) {
    const int t0k = kt * 64;
    u16* Kd = lds + buf * 8192;
    u16* Vd = lds + 16384 + buf * 8192;
#pragma unroll
    for (int j = 0; j < 2; ++j) {
      int c = tid + j * 512;
      int row = c >> 4;
      int sboff = ((c & 15) * 16) ^ ((row & 15) << 4);
      gload_lds16(Kb + (size_t)(t0k + row) * 128 + (sboff >> 1),
                  Kd + (size_t)(wbase + j * 512) * 8);
    }
#pragma unroll
    for (int j = 0; j < 2; ++j) {
      int c = tid + j * 512;
      int d = c >> 3;
      int sboff = ((c & 7) * 16) ^ ((d & 7) << 4);
      gload_lds16(Vtb + (size_t)d * 2048 + t0k + (sboff >> 1),
                  Vd + (size_t)(wbase + j * 512) * 8);
    }
  };

  for (int pass = 0; pass < 2; ++pass) {
    const int qt = pass ? (7 - pa) : pa;
    const int q0 = qt * 256;
    const int wrow0 = q0 + w * 32;    // this wave's first q row
    const int qg = wrow0 + l5;        // this lane's q row

    const u16* Qb = Q + ((size_t)((b * 16 + h) * 2048 + wrow0)) * 128;
    bf16x8 qf[8];
#pragma unroll
    for (int ks = 0; ks < 8; ++ks)
      qf[ks] = *(const bf16x8*)(Qb + (size_t)l5 * 128 + ks * 16 + hi * 8);

    f32x16 oacc[4];
#pragma unroll
    for (int i = 0; i < 4; ++i) oacc[i] = (f32x16)0.0f;
    float m = -3.0e38f, l = 0.0f;

    const int nkt = 4 * qt + 4;
    stageKV(0, 0);

    for (int kt = 0; kt < nkt; ++kt) {
      const int t0 = kt * 64;
      const int cur = kt & 1;
      if (kt + 1 < nkt) {
        stageKV(kt + 1, cur ^ 1);
        asm volatile("s_waitcnt vmcnt(4)" ::: "memory");
      } else {
        asm volatile("s_waitcnt vmcnt(0)" ::: "memory");
      }
      __builtin_amdgcn_s_barrier();    // buf[cur] staged by all waves

      if (t0 <= wrow0 + 31) {
        const char* ksb = (const char*)(lds + cur * 8192);
        const char* vtb = (const char*)(lds + 16384 + cur * 8192);

        // S^T = mfma(K, Q): p[kt2*16+r] = S[kv][q], kv = kt2*32 + (r&3)+8*(r>>2)+4*hi
        float p[32];
#pragma unroll
        for (int kt2 = 0; kt2 < 2; ++kt2) {
          f32x16 sacc = (f32x16)0.0f;
          int row = kt2 * 32 + l5;
          __builtin_amdgcn_s_setprio(1);
#pragma unroll
          for (int ks = 0; ks < 8; ++ks) {
            bf16x8 kf = *(const bf16x8*)(ksb + row * 256 + ((ks * 32 + hi * 16) ^ ((row & 15) << 4)));
            sacc = __builtin_amdgcn_mfma_f32_32x32x16_bf16(kf, qf[ks], sacc, 0, 0, 0);
          }
          __builtin_amdgcn_s_setprio(0);
#pragma unroll
          for (int r = 0; r < 16; ++r) p[kt2 * 16 + r] = sacc[r];
        }

        if (t0 + 63 > wrow0) {  // straddles diagonal: causal mask
#pragma unroll
          for (int kt2 = 0; kt2 < 2; ++kt2)
#pragma unroll
            for (int r = 0; r < 16; ++r) {
              int kvg = t0 + kt2 * 32 + (r & 3) + 8 * (r >> 2) + 4 * hi;
              if (kvg > qg) p[kt2 * 16 + r] = -3.0e38f;
            }
        }

        // in-lane row max + cross-half combine
        float mx[16];
#pragma unroll
        for (int i = 0; i < 16; ++i) mx[i] = fmaxf(p[i], p[i + 16]);
#pragma unroll
        for (int i = 0; i < 8; ++i) mx[i] = fmaxf(mx[i], mx[i + 8]);
#pragma unroll
        for (int i = 0; i < 4; ++i) mx[i] = fmaxf(mx[i], mx[i + 4]);
        float rm = fmaxf(fmaxf(mx[0], mx[1]), fmaxf(mx[2], mx[3]));
        rm = fmaxf(rm, __shfl_xor(rm, 32));

        bool defer = __all(rm <= m + 8.0f);
        if (!defer) {
          float mnew = fmaxf(m, rm);
          float sc = exp2f(m - mnew);
          m = mnew;
          l *= sc;
#pragma unroll
          for (int i = 0; i < 4; ++i)
#pragma unroll
            for (int r = 0; r < 16; ++r) oacc[i][r] *= sc;
        }

        // p = exp2(S - m); in-lane sum
#pragma unroll
        for (int i = 0; i < 32; ++i) p[i] = exp2f(p[i] - m);
        float sm[16];
#pragma unroll
        for (int i = 0; i < 16; ++i) sm[i] = p[i] + p[i + 16];
#pragma unroll
        for (int i = 0; i < 8; ++i) sm[i] += sm[i + 8];
#pragma unroll
        for (int i = 0; i < 4; ++i) sm[i] += sm[i + 4];
        float s2 = (sm[0] + sm[1]) + (sm[2] + sm[3]);
        s2 += __shfl_xor(s2, 32);
        l += s2;

        // P pack + permlane32_swap redistribute + PV: O^T += mfma(A=V^T, B=P)
#pragma unroll
        for (int kt2 = 0; kt2 < 2; ++kt2) {
#pragma unroll
          for (int sl = 0; sl < 2; ++sl) {
            int base = kt2 * 16 + sl * 8;
            unsigned A0 = cvtpk(p[base + 0], p[base + 1]);
            unsigned A1 = cvtpk(p[base + 2], p[base + 3]);
            unsigned A2 = cvtpk(p[base + 4], p[base + 5]);
            unsigned A3 = cvtpk(p[base + 6], p[base + 7]);
            asm volatile("v_permlane32_swap_b32 %0, %1" : "+v"(A0), "+v"(A2));
            asm volatile("v_permlane32_swap_b32 %0, %1" : "+v"(A1), "+v"(A3));
            union { unsigned u[4]; bf16x8 v; } pf;
            pf.u[0] = A0;
            pf.u[1] = A1;
            pf.u[2] = A2;
            pf.u[3] = A3;
            int s = kt2 * 2 + sl;
            __builtin_amdgcn_s_setprio(1);
#pragma unroll
            for (int dt = 0; dt < 4; ++dt) {
              int row = dt * 32 + l5;
              bf16x8 vb = *(const bf16x8*)(vtb + row * 128 + ((s * 32 + hi * 16) ^ ((row & 7) << 4)));
              oacc[dt] = __builtin_amdgcn_mfma_f32_32x32x16_bf16(vb, pf.v, oacc[dt], 0, 0, 0);
            }
            __builtin_amdgcn_s_setprio(0);
          }
        }
      }

      asm volatile("s_waitcnt lgkmcnt(0)" ::: "memory");
      __builtin_amdgcn_s_barrier();    // all waves done reading buf[cur]
    }

    // normalize in-lane; two half-passes through OS overlay (waves 0-3, then 4-7)
    float inv = 1.0f / l;
    __syncthreads();
    for (int half = 0; half < 2; ++half) {
      if ((w >> 2) == half) {
        u16* OSw = lds + (w & 3) * 4352;     // [32 q][136] padded
#pragma unroll
        for (int dt = 0; dt < 4; ++dt)
#pragma unroll
          for (int r = 0; r < 16; ++r) {
            int d = dt * 32 + (r & 3) + 8 * (r >> 2) + 4 * hi;
            OSw[l5 * 136 + d] = f2bf(oacc[dt][r] * inv);
          }
      }
      __syncthreads();
      u16* Ob = O + ((size_t)(b * 2048 + q0 + half * 128)) * 2048 + h * 128;
#pragma unroll
      for (int j = 0; j < 4; ++j) {
        int c = tid + j * 512;
        int row = c >> 4, col = c & 15;
        *(bf16x8*)(Ob + (size_t)row * 2048 + col * 8) =
            *(const bf16x8*)&lds[(row >> 5) * 4352 + (row & 31) * 136 + col * 8];
      }
      __syncthreads();
    }
  }
}

extern "C" void kernel_launch(void* const* d_in, const int* in_sizes, int n_in,
                              void* d_out, int out_size, void* d_ws, size_t ws_size,
                              hipStream_t stream) {
  (void)in_sizes; (void)n_in; (void)out_size; (void)ws_size;
  const float* x    = (const float*)d_in[0];
  const float* Wq   = (const float*)d_in[1];
  const float* Wk   = (const float*)d_in[2];
  const float* Wv   = (const float*)d_in[3];
  const float* Wo   = (const float*)d_in[4];
  const float* cosp = (const float*)d_in[5];
  const float* sinp = (const float*)d_in[6];

  u16* ws  = (u16*)d_ws;
  u16* xbf = ws;               // 16,777,216 elems (B*T x C)  -- reused as attn out
  u16* Wqb = xbf + 16777216;   //  4,194,304
  u16* Wkb = Wqb + 4194304;    //  1,048,576  } contiguous 1024x2048 KV weight
  u16* Wvb = Wkb + 1048576;    //  1,048,576  }
  u16* Wob = Wvb + 1048576;    //  4,194,304
  u16* Qb  = Wob + 4194304;    // 16,777,216 (B,H,T,D)
  u16* Kb  = Qb + 16777216;    //  4,194,304 (B,HKV,T,D)
  u16* Vb  = Kb + 4194304;     //  4,194,304 (B,HKV,D,T)  == V^T
  u16* AO  = xbf;              // attention output (B,T,C), reuses x region

  cast_all_kernel<<<2048, 256, 0, stream>>>(x, Wq, Wk, Wv, Wo, ws);

  const float qscale = (float)(1.4426950408889634 / sqrt(128.0));

  gemm_bt256<0><<<dim3(8, 32), 512, 0, stream>>>(xbf, Wqb, Qb, 8192, 2048, 2048, cosp, sinp, qscale);
  gemm_bt<3><<<dim3(8, 64), 256, 0, stream>>>(xbf, Wkb, Kb, Vb, 8192, 1024, 2048, cosp, sinp, 1.0f);

  attn_kernel<<<256, 512, 0, stream>>>(Qb, Kb, Vb, AO);

  gemm_bt256<2><<<dim3(8, 32), 512, 0, stream>>>(AO, Wob, d_out, 8192, 2048, 2048, nullptr, nullptr, 1.0f);
}

// Round 15
// 317.918 us; speedup vs baseline: 1.1806x; 1.0238x over previous
//
#include <hip/hip_runtime.h>
#include <cmath>

typedef __attribute__((ext_vector_type(8))) short bf16x8;
typedef __attribute__((ext_vector_type(4))) float f32x4;
typedef __attribute__((ext_vector_type(16))) float f32x16;
typedef unsigned short u16;

__device__ __forceinline__ u16 f2bf(float f) {
  union { float f; unsigned u; } x; x.f = f;
  return (u16)((x.u + 0x7FFFu + ((x.u >> 16) & 1u)) >> 16);
}

__device__ __forceinline__ unsigned cvtpk(float lo, float hi) {
  unsigned r;
  asm("v_cvt_pk_bf16_f32 %0, %1, %2" : "=v"(r) : "v"(lo), "v"(hi));
  return r;
}

__device__ __forceinline__ void gload_lds16(const void* g, void* l) {
  __builtin_amdgcn_global_load_lds((const __attribute__((address_space(1))) unsigned*)g,
                                   (__attribute__((address_space(3))) unsigned*)l,
                                   16, 0, 0);
}

// One fused cast: dst segments are contiguous in ws:
// [x 16777216 | wq 4194304 | wk 1048576 | wv 1048576 | wo 4194304]
__global__ __launch_bounds__(256) void cast_all_kernel(const float* __restrict__ x,
                                                       const float* __restrict__ wq,
                                                       const float* __restrict__ wk,
                                                       const float* __restrict__ wv,
                                                       const float* __restrict__ wo,
                                                       u16* __restrict__ out) {
  const long b1 = 16777216, b2 = 20971520, b3 = 22020096, b4 = 23068672, b5 = 27262976;
  long i = (long)blockIdx.x * blockDim.x + threadIdx.x;
  long stride = (long)gridDim.x * blockDim.x;
  for (long j = i * 4; j < b5; j += stride * 4) {
    const float* src; long off;
    if (j < b1)      { src = x;  off = j; }
    else if (j < b2) { src = wq; off = j - b1; }
    else if (j < b3) { src = wk; off = j - b2; }
    else if (j < b4) { src = wv; off = j - b3; }
    else             { src = wo; off = j - b4; }
    float4 v = *(const float4*)(src + off);
    ushort4 o;
    o.x = f2bf(v.x); o.y = f2bf(v.y); o.z = f2bf(v.z); o.w = f2bf(v.w);
    *(ushort4*)(out + j) = o;
  }
}

// ---------------- 256x256 counted-vmcnt deep-pipeline GEMM (round-12 form) ----------------
// EPI 0: RoPE + scale, bf16 to (b, h=col>>7, t, d=col&127). EPI 2: f32 [M,N].
template <int EPI>
__global__ __launch_bounds__(512, 2) void gemm_bt256(const u16* __restrict__ A,
                                                     const u16* __restrict__ B,
                                                     void* __restrict__ outp,
                                                     int M, int N, int K,
                                                     const float* __restrict__ cosp,
                                                     const float* __restrict__ sinp,
                                                     float scale) {
  __shared__ u16 lds[65536];   // [buf][A 256x64 | B 256x64], 128KB
  const int tid = threadIdx.x;
  const int lane = tid & 63;
  const int l16 = lane & 15, lhi = lane >> 4;
  const int w = tid >> 6;
  const int wr = w >> 2, wc = w & 3;
  const int m0 = blockIdx.y * 256;
  const int n0 = blockIdx.x * 256;

  f32x4 acc[8][4];
#pragma unroll
  for (int i = 0; i < 8; ++i)
#pragma unroll
    for (int j = 0; j < 4; ++j) acc[i][j] = (f32x4)0.0f;

  const int NT = K >> 6;

  auto stage = [&](int t, int buf) {
    const int k0 = t << 6;
    u16* Ad = lds + buf * 32768;
    u16* Bd = Ad + 16384;
#pragma unroll
    for (int j = 0; j < 4; ++j) {
      int c = tid + j * 512;
      int row = c >> 3;
      int sboff = ((c & 7) * 16) ^ ((row & 7) << 4);
      gload_lds16(A + (size_t)(m0 + row) * K + k0 + (sboff >> 1), Ad + (size_t)c * 8);
    }
#pragma unroll
    for (int j = 0; j < 4; ++j) {
      int c = tid + j * 512;
      int row = c >> 3;
      int sboff = ((c & 7) * 16) ^ ((row & 7) << 4);
      gload_lds16(B + (size_t)(n0 + row) * K + k0 + (sboff >> 1), Bd + (size_t)c * 8);
    }
  };

  stage(0, 0);
  stage(1, 1);

  for (int t = 0; t < NT; ++t) {
    const int cur = t & 1;
    if (t + 1 < NT) { asm volatile("s_waitcnt vmcnt(8)" ::: "memory"); }
    else            { asm volatile("s_waitcnt vmcnt(0)" ::: "memory"); }
    __builtin_amdgcn_s_barrier();
    const char* Ab = (const char*)(lds + cur * 32768);
    const char* Bb = (const char*)(lds + cur * 32768 + 16384);
#pragma unroll
    for (int qm = 0; qm < 2; ++qm)
#pragma unroll
      for (int qn = 0; qn < 2; ++qn) {
        bf16x8 af[4][2], bfr[2][2];
#pragma unroll
        for (int mi = 0; mi < 4; ++mi) {
          int ra = wr * 128 + qm * 64 + mi * 16 + l16;
#pragma unroll
          for (int kk = 0; kk < 2; ++kk)
            af[mi][kk] = *(const bf16x8*)(Ab + ra * 128 + ((kk * 64 + lhi * 16) ^ ((ra & 7) << 4)));
        }
#pragma unroll
        for (int ni = 0; ni < 2; ++ni) {
          int rb = wc * 64 + qn * 32 + ni * 16 + l16;
#pragma unroll
          for (int kk = 0; kk < 2; ++kk)
            bfr[ni][kk] = *(const bf16x8*)(Bb + rb * 128 + ((kk * 64 + lhi * 16) ^ ((rb & 7) << 4)));
        }
        __builtin_amdgcn_s_setprio(1);
#pragma unroll
        for (int kk = 0; kk < 2; ++kk)
#pragma unroll
          for (int mi = 0; mi < 4; ++mi)
#pragma unroll
            for (int ni = 0; ni < 2; ++ni)
              acc[qm * 4 + mi][qn * 2 + ni] = __builtin_amdgcn_mfma_f32_16x16x32_bf16(
                  af[mi][kk], bfr[ni][kk], acc[qm * 4 + mi][qn * 2 + ni], 0, 0, 0);
        __builtin_amdgcn_s_setprio(0);
      }
    asm volatile("s_waitcnt lgkmcnt(0)" ::: "memory");
    __builtin_amdgcn_s_barrier();
    if (t + 2 < NT) stage(t + 2, cur);
  }

  if (EPI == 2) {
    float* o = (float*)outp;
#pragma unroll
    for (int mi8 = 0; mi8 < 8; ++mi8)
#pragma unroll
      for (int r = 0; r < 4; ++r) {
        int row = m0 + wr * 128 + mi8 * 16 + lhi * 4 + r;
#pragma unroll
        for (int nj = 0; nj < 4; ++nj) {
          int col = n0 + wc * 64 + nj * 16 + l16;
          o[(size_t)row * N + col] = acc[mi8][nj][r];
        }
      }
  } else {
    u16* o = (u16*)outp;
    const int nheads = N >> 7;
#pragma unroll
    for (int mi8 = 0; mi8 < 8; ++mi8)
#pragma unroll
      for (int r = 0; r < 4; ++r) {
        int row = m0 + wr * 128 + mi8 * 16 + lhi * 4 + r;
        int b = row >> 11;
        int tt = row & 2047;
#pragma unroll
        for (int nj = 0; nj < 4; ++nj) {
          int col = n0 + wc * 64 + nj * 16 + l16;
          int hh = col >> 7, dd = col & 127;
          float v = acc[mi8][nj][r];
          float p = __shfl_xor(v, 1);
          float c = cosp[tt * 64 + (dd >> 1)];
          float s = sinp[tt * 64 + (dd >> 1)];
          v = (lane & 1) ? fmaf(p, s, v * c) : fmaf(v, c, -p * s);
          v *= scale;
          o[((size_t)(b * nheads + hh) * 2048 + tt) * 128 + dd] = f2bf(v);
        }
      }
  }
}

// ---------------- 128x128 2-phase GEMM (KV projection only, round-12 form) ----------------
template <int EPI>
__global__ __launch_bounds__(256) void gemm_bt(const u16* __restrict__ A,
                                               const u16* __restrict__ B,
                                               void* __restrict__ outp,
                                               u16* __restrict__ vtp,
                                               int M, int N, int K,
                                               const float* __restrict__ cosp,
                                               const float* __restrict__ sinp,
                                               float scale) {
  __shared__ u16 As[128 * 64];
  __shared__ u16 Bs[128 * 64];
  const int tid = threadIdx.x;
  const int lane = tid & 63;
  const int l16 = lane & 15, lhi = lane >> 4;
  const int w = tid >> 6;
  const int wr = w >> 1, wc = w & 1;
  const int m0 = blockIdx.y * 128;
  const int n0 = blockIdx.x * 128;
  const int wbase = tid - lane;

  f32x4 acc[4][4];
#pragma unroll
  for (int i = 0; i < 4; ++i)
#pragma unroll
    for (int j = 0; j < 4; ++j) acc[i][j] = (f32x4)0.0f;

  for (int k0 = 0; k0 < K; k0 += 64) {
    __syncthreads();
#pragma unroll
    for (int j = 0; j < 4; ++j) {
      int c = tid + j * 256;
      gload_lds16(A + (size_t)(m0 + (c >> 3)) * K + k0 + (c & 7) * 8,
                  As + (size_t)(wbase + j * 256) * 8);
    }
#pragma unroll
    for (int j = 0; j < 4; ++j) {
      int c = tid + j * 256;
      gload_lds16(B + (size_t)(n0 + (c >> 3)) * K + k0 + (c & 7) * 8,
                  Bs + (size_t)(wbase + j * 256) * 8);
    }
    __syncthreads();
#pragma unroll
    for (int kk = 0; kk < 64; kk += 32) {
      bf16x8 af[4], bfr[4];
#pragma unroll
      for (int mi = 0; mi < 4; ++mi)
        af[mi] = *(const bf16x8*)&As[(wr * 64 + mi * 16 + l16) * 64 + kk + lhi * 8];
#pragma unroll
      for (int ni = 0; ni < 4; ++ni)
        bfr[ni] = *(const bf16x8*)&Bs[(wc * 64 + ni * 16 + l16) * 64 + kk + lhi * 8];
#pragma unroll
      for (int mi = 0; mi < 4; ++mi)
#pragma unroll
        for (int ni = 0; ni < 4; ++ni)
          acc[mi][ni] = __builtin_amdgcn_mfma_f32_16x16x32_bf16(af[mi], bfr[ni], acc[mi][ni], 0, 0, 0);
    }
  }

  {  // EPI == 3 (merged KV)
    const int bx = blockIdx.x;
    if (bx < 4) {
      u16* o = (u16*)outp;
#pragma unroll
      for (int mi = 0; mi < 4; ++mi)
#pragma unroll
        for (int r = 0; r < 4; ++r) {
          int row = m0 + wr * 64 + mi * 16 + lhi * 4 + r;
          int b = row >> 11;
          int t = row & 2047;
          size_t base = ((size_t)(b * 4 + bx) * 2048 + t) * 128;
#pragma unroll
          for (int ni = 0; ni < 4; ++ni) {
            int d = wc * 64 + ni * 16 + l16;
            float v = acc[mi][ni][r];
            float p = __shfl_xor(v, 1);
            float c = cosp[t * 64 + (d >> 1)];
            float s = sinp[t * 64 + (d >> 1)];
            v = (lane & 1) ? fmaf(p, s, v * c) : fmaf(v, c, -p * s);
            o[base + d] = f2bf(v);
          }
        }
    } else {
      const int kvh = bx - 4;
#pragma unroll
      for (int mi = 0; mi < 4; ++mi)
#pragma unroll
        for (int r = 0; r < 4; ++r) {
          int row = m0 + wr * 64 + mi * 16 + lhi * 4 + r;
          int b = row >> 11;
          int t = row & 2047;
          size_t base = ((size_t)(b * 4 + kvh) * 128) * 2048 + t;
#pragma unroll
          for (int ni = 0; ni < 4; ++ni) {
            int d = wc * 64 + ni * 16 + l16;
            vtp[base + (size_t)d * 2048] = f2bf(acc[mi][ni][r]);
          }
        }
    }
  }
}

// ---------------- Flash attention: KVBLK=128, paired q-tiles ----------------
// Grid 256 = 64 (h,b) x 4 pairs; block = 8 waves x 32 q-rows, 256-row q-tile,
// pair (pa, 7-pa) -> 18 barrier-locked sections per block (was 36 at KVBLK=64;
// rounds 9/12/14 showed attn invariant to occupancy config -> latency-bound on
// barrier-pair count, so halve it). Per staged 128-kv tile the round-12-verified
// 64-kv math body runs twice (sub 0/1): Ks sub-offset 8192 u16; V col +sub*128 B
// (outside the XOR: key (d&7)<<4 < 128 preserves the half bit).
// LDS 128KB (buf: K 32KB | V 32KB, x2) -> 1 block/CU.
__global__ __launch_bounds__(512, 2) void attn_kernel(const u16* __restrict__ Q,
                                                      const u16* __restrict__ Kp,
                                                      const u16* __restrict__ Vtp,
                                                      u16* __restrict__ O) {
  __shared__ u16 lds[65536];          // 128KB: buf b at b*32768 (K 16384 | V 16384 u16)

  const int tid = threadIdx.x;
  const int lane = tid & 63;
  const int w = tid >> 6;             // 0..7
  const int l5 = lane & 31, hi = lane >> 5;
  const int bid = blockIdx.x;
  const int hb = bid & 63;
  const int pa = bid >> 6;            // 0..3: q-tile pair (pa, 7-pa)
  const int h = hb >> 2;
  const int b = hb & 3;
  const int kvh = h >> 2;
  const int wbase = tid - lane;

  const u16* Kb = Kp + (size_t)(b * 4 + kvh) * 2048 * 128;
  const u16* Vtb = Vtp + (size_t)(b * 4 + kvh) * 128 * 2048;

  auto stageKV = [&](int kt, int buf) {
    const int t0k = kt * 128;
    u16* Kd = lds + buf * 32768;
    u16* Vd = Kd + 16384;
#pragma unroll
    for (int j = 0; j < 4; ++j) {
      int c = tid + j * 512;
      int row = c >> 4;                                  // 0..127
      int sboff = ((c & 15) * 16) ^ ((row & 15) << 4);   // byte in 256B row
      gload_lds16(Kb + (size_t)(t0k + row) * 128 + (sboff >> 1),
                  Kd + (size_t)(wbase + j * 512) * 8);
    }
#pragma unroll
    for (int j = 0; j < 4; ++j) {
      int c = tid + j * 512;
      int d = c >> 4;                                    // 0..127
      int sboff = ((c & 15) * 16) ^ ((d & 7) << 4);      // byte in 256B row
      gload_lds16(Vtb + (size_t)d * 2048 + t0k + (sboff >> 1),
                  Vd + (size_t)(wbase + j * 512) * 8);
    }
  };

  for (int pass = 0; pass < 2; ++pass) {
    const int qt = pass ? (7 - pa) : pa;
    const int q0 = qt * 256;
    const int wrow0 = q0 + w * 32;    // this wave's first q row
    const int qg = wrow0 + l5;        // this lane's q row

    const u16* Qb = Q + ((size_t)((b * 16 + h) * 2048 + wrow0)) * 128;
    bf16x8 qf[8];
#pragma unroll
    for (int ks = 0; ks < 8; ++ks)
      qf[ks] = *(const bf16x8*)(Qb + (size_t)l5 * 128 + ks * 16 + hi * 8);

    f32x16 oacc[4];
#pragma unroll
    for (int i = 0; i < 4; ++i) oacc[i] = (f32x16)0.0f;
    float m = -3.0e38f, l = 0.0f;

    const int nkt = 2 * qt + 2;       // 128-kv tiles
    stageKV(0, 0);

    for (int kt = 0; kt < nkt; ++kt) {
      const int cur = kt & 1;
      if (kt + 1 < nkt) {
        stageKV(kt + 1, cur ^ 1);
        asm volatile("s_waitcnt vmcnt(8)" ::: "memory");
      } else {
        asm volatile("s_waitcnt vmcnt(0)" ::: "memory");
      }
      __builtin_amdgcn_s_barrier();    // buf[cur] staged by all waves

#pragma unroll
      for (int sub = 0; sub < 2; ++sub) {
        const int t0s = kt * 128 + sub * 64;
        if (t0s <= wrow0 + 31) {       // wave-uniform guard per 64-kv subtile
          const char* ksb = (const char*)(lds + cur * 32768 + sub * 8192);
          const char* vtb = (const char*)(lds + cur * 32768 + 16384);
          const int vsub = sub * 128;  // byte col offset into V rows

          // S^T = mfma(K, Q): p[kt2*16+r] = S[kv][q], kv = kt2*32 + (r&3)+8*(r>>2)+4*hi
          float p[32];
#pragma unroll
          for (int kt2 = 0; kt2 < 2; ++kt2) {
            f32x16 sacc = (f32x16)0.0f;
            int row = kt2 * 32 + l5;
            __builtin_amdgcn_s_setprio(1);
#pragma unroll
            for (int ks = 0; ks < 8; ++ks) {
              bf16x8 kf = *(const bf16x8*)(ksb + row * 256 + ((ks * 32 + hi * 16) ^ ((row & 15) << 4)));
              sacc = __builtin_amdgcn_mfma_f32_32x32x16_bf16(kf, qf[ks], sacc, 0, 0, 0);
            }
            __builtin_amdgcn_s_setprio(0);
#pragma unroll
            for (int r = 0; r < 16; ++r) p[kt2 * 16 + r] = sacc[r];
          }

          if (t0s + 63 > wrow0) {  // straddles diagonal: causal mask
#pragma unroll
            for (int kt2 = 0; kt2 < 2; ++kt2)
#pragma unroll
              for (int r = 0; r < 16; ++r) {
                int kvg = t0s + kt2 * 32 + (r & 3) + 8 * (r >> 2) + 4 * hi;
                if (kvg > qg) p[kt2 * 16 + r] = -3.0e38f;
              }
          }

          // in-lane row max + cross-half combine
          float mx[16];
#pragma unroll
          for (int i = 0; i < 16; ++i) mx[i] = fmaxf(p[i], p[i + 16]);
#pragma unroll
          for (int i = 0; i < 8; ++i) mx[i] = fmaxf(mx[i], mx[i + 8]);
#pragma unroll
          for (int i = 0; i < 4; ++i) mx[i] = fmaxf(mx[i], mx[i + 4]);
          float rm = fmaxf(fmaxf(mx[0], mx[1]), fmaxf(mx[2], mx[3]));
          rm = fmaxf(rm, __shfl_xor(rm, 32));

          bool defer = __all(rm <= m + 8.0f);
          if (!defer) {
            float mnew = fmaxf(m, rm);
            float sc = exp2f(m - mnew);
            m = mnew;
            l *= sc;
#pragma unroll
            for (int i = 0; i < 4; ++i)
#pragma unroll
              for (int r = 0; r < 16; ++r) oacc[i][r] *= sc;
          }

          // p = exp2(S - m); in-lane sum
#pragma unroll
          for (int i = 0; i < 32; ++i) p[i] = exp2f(p[i] - m);
          float sm[16];
#pragma unroll
          for (int i = 0; i < 16; ++i) sm[i] = p[i] + p[i + 16];
#pragma unroll
          for (int i = 0; i < 8; ++i) sm[i] += sm[i + 8];
#pragma unroll
          for (int i = 0; i < 4; ++i) sm[i] += sm[i + 4];
          float s2 = (sm[0] + sm[1]) + (sm[2] + sm[3]);
          s2 += __shfl_xor(s2, 32);
          l += s2;

          // P pack + permlane32_swap redistribute + PV: O^T += mfma(A=V^T, B=P)
#pragma unroll
          for (int kt2 = 0; kt2 < 2; ++kt2) {
#pragma unroll
            for (int sl = 0; sl < 2; ++sl) {
              int base = kt2 * 16 + sl * 8;
              unsigned A0 = cvtpk(p[base + 0], p[base + 1]);
              unsigned A1 = cvtpk(p[base + 2], p[base + 3]);
              unsigned A2 = cvtpk(p[base + 4], p[base + 5]);
              unsigned A3 = cvtpk(p[base + 6], p[base + 7]);
              asm volatile("v_permlane32_swap_b32 %0, %1" : "+v"(A0), "+v"(A2));
              asm volatile("v_permlane32_swap_b32 %0, %1" : "+v"(A1), "+v"(A3));
              union { unsigned u[4]; bf16x8 v; } pf;
              pf.u[0] = A0;
              pf.u[1] = A1;
              pf.u[2] = A2;
              pf.u[3] = A3;
              int s = kt2 * 2 + sl;
              __builtin_amdgcn_s_setprio(1);
#pragma unroll
              for (int dt = 0; dt < 4; ++dt) {
                int row = dt * 32 + l5;
                bf16x8 vb = *(const bf16x8*)(vtb + row * 256 + vsub +
                                             ((s * 32 + hi * 16) ^ ((row & 7) << 4)));
                oacc[dt] = __builtin_amdgcn_mfma_f32_32x32x16_bf16(vb, pf.v, oacc[dt], 0, 0, 0);
              }
              __builtin_amdgcn_s_setprio(0);
            }
          }
        }
      }

      asm volatile("s_waitcnt lgkmcnt(0)" ::: "memory");
      __builtin_amdgcn_s_barrier();    // all waves done reading buf[cur]
    }

    // normalize in-lane; two half-passes through OS overlay (waves 0-3, then 4-7)
    float inv = 1.0f / l;
    __syncthreads();
    for (int half = 0; half < 2; ++half) {
      if ((w >> 2) == half) {
        u16* OSw = lds + (w & 3) * 4352;     // [32 q][136] padded
#pragma unroll
        for (int dt = 0; dt < 4; ++dt)
#pragma unroll
          for (int r = 0; r < 16; ++r) {
            int d = dt * 32 + (r & 3) + 8 * (r >> 2) + 4 * hi;
            OSw[l5 * 136 + d] = f2bf(oacc[dt][r] * inv);
          }
      }
      __syncthreads();
      u16* Ob = O + ((size_t)(b * 2048 + q0 + half * 128)) * 2048 + h * 128;
#pragma unroll
      for (int j = 0; j < 4; ++j) {
        int c = tid + j * 512;
        int row = c >> 4, col = c & 15;
        *(bf16x8*)(Ob + (size_t)row * 2048 + col * 8) =
            *(const bf16x8*)&lds[(row >> 5) * 4352 + (row & 31) * 136 + col * 8];
      }
      __syncthreads();
    }
  }
}

extern "C" void kernel_launch(void* const* d_in, const int* in_sizes, int n_in,
                              void* d_out, int out_size, void* d_ws, size_t ws_size,
                              hipStream_t stream) {
  (void)in_sizes; (void)n_in; (void)out_size; (void)ws_size;
  const float* x    = (const float*)d_in[0];
  const float* Wq   = (const float*)d_in[1];
  const float* Wk   = (const float*)d_in[2];
  const float* Wv   = (const float*)d_in[3];
  const float* Wo   = (const float*)d_in[4];
  const float* cosp = (const float*)d_in[5];
  const float* sinp = (const float*)d_in[6];

  u16* ws  = (u16*)d_ws;
  u16* xbf = ws;               // 16,777,216 elems (B*T x C)  -- reused as attn out
  u16* Wqb = xbf + 16777216;   //  4,194,304
  u16* Wkb = Wqb + 4194304;    //  1,048,576  } contiguous 1024x2048 KV weight
  u16* Wvb = Wkb + 1048576;    //  1,048,576  }
  u16* Wob = Wvb + 1048576;    //  4,194,304
  u16* Qb  = Wob + 4194304;    // 16,777,216 (B,H,T,D)
  u16* Kb  = Qb + 16777216;    //  4,194,304 (B,HKV,T,D)
  u16* Vb  = Kb + 4194304;     //  4,194,304 (B,HKV,D,T)  == V^T
  u16* AO  = xbf;              // attention output (B,T,C), reuses x region

  cast_all_kernel<<<2048, 256, 0, stream>>>(x, Wq, Wk, Wv, Wo, ws);

  const float qscale = (float)(1.4426950408889634 / sqrt(128.0));

  gemm_bt256<0><<<dim3(8, 32), 512, 0, stream>>>(xbf, Wqb, Qb, 8192, 2048, 2048, cosp, sinp, qscale);
  gemm_bt<3><<<dim3(8, 64), 256, 0, stream>>>(xbf, Wkb, Kb, Vb, 8192, 1024, 2048, cosp, sinp, 1.0f);

  attn_kernel<<<256, 512, 0, stream>>>(Qb, Kb, Vb, AO);

  gemm_bt256<2><<<dim3(8, 32), 512, 0, stream>>>(AO, Wob, d_out, 8192, 2048, 2048, nullptr, nullptr, 1.0f);
}

// Round 16
// 312.290 us; speedup vs baseline: 1.2018x; 1.0180x over previous
//
#include <hip/hip_runtime.h>
#include <cmath>

typedef __attribute__((ext_vector_type(8))) short bf16x8;
typedef __attribute__((ext_vector_type(4))) float f32x4;
typedef __attribute__((ext_vector_type(16))) float f32x16;
typedef unsigned short u16;

__device__ __forceinline__ u16 f2bf(float f) {
  union { float f; unsigned u; } x; x.f = f;
  return (u16)((x.u + 0x7FFFu + ((x.u >> 16) & 1u)) >> 16);
}

__device__ __forceinline__ unsigned cvtpk(float lo, float hi) {
  unsigned r;
  asm("v_cvt_pk_bf16_f32 %0, %1, %2" : "=v"(r) : "v"(lo), "v"(hi));
  return r;
}

__device__ __forceinline__ void gload_lds16(const void* g, void* l) {
  __builtin_amdgcn_global_load_lds((const __attribute__((address_space(1))) unsigned*)g,
                                   (__attribute__((address_space(3))) unsigned*)l,
                                   16, 0, 0);
}

// One fused cast: dst segments are contiguous in ws:
// [x 16777216 | wq 4194304 | wk 1048576 | wv 1048576 | wo 4194304]
__global__ __launch_bounds__(256) void cast_all_kernel(const float* __restrict__ x,
                                                       const float* __restrict__ wq,
                                                       const float* __restrict__ wk,
                                                       const float* __restrict__ wv,
                                                       const float* __restrict__ wo,
                                                       u16* __restrict__ out) {
  const long b1 = 16777216, b2 = 20971520, b3 = 22020096, b4 = 23068672, b5 = 27262976;
  long i = (long)blockIdx.x * blockDim.x + threadIdx.x;
  long stride = (long)gridDim.x * blockDim.x;
  for (long j = i * 4; j < b5; j += stride * 4) {
    const float* src; long off;
    if (j < b1)      { src = x;  off = j; }
    else if (j < b2) { src = wq; off = j - b1; }
    else if (j < b3) { src = wk; off = j - b2; }
    else if (j < b4) { src = wv; off = j - b3; }
    else             { src = wo; off = j - b4; }
    float4 v = *(const float4*)(src + off);
    ushort4 o;
    o.x = f2bf(v.x); o.y = f2bf(v.y); o.z = f2bf(v.z); o.w = f2bf(v.w);
    *(ushort4*)(out + j) = o;
  }
}

// ---------------- 256x256 counted-vmcnt deep-pipeline GEMM (round-12 form) ----------------
// EPI 0: RoPE + scale, bf16 to (b, h=col>>7, t, d=col&127). EPI 2: f32 [M,N].
template <int EPI>
__global__ __launch_bounds__(512, 2) void gemm_bt256(const u16* __restrict__ A,
                                                     const u16* __restrict__ B,
                                                     void* __restrict__ outp,
                                                     int M, int N, int K,
                                                     const float* __restrict__ cosp,
                                                     const float* __restrict__ sinp,
                                                     float scale) {
  __shared__ u16 lds[65536];   // [buf][A 256x64 | B 256x64], 128KB
  const int tid = threadIdx.x;
  const int lane = tid & 63;
  const int l16 = lane & 15, lhi = lane >> 4;
  const int w = tid >> 6;
  const int wr = w >> 2, wc = w & 3;
  const int m0 = blockIdx.y * 256;
  const int n0 = blockIdx.x * 256;

  f32x4 acc[8][4];
#pragma unroll
  for (int i = 0; i < 8; ++i)
#pragma unroll
    for (int j = 0; j < 4; ++j) acc[i][j] = (f32x4)0.0f;

  const int NT = K >> 6;

  auto stage = [&](int t, int buf) {
    const int k0 = t << 6;
    u16* Ad = lds + buf * 32768;
    u16* Bd = Ad + 16384;
#pragma unroll
    for (int j = 0; j < 4; ++j) {
      int c = tid + j * 512;
      int row = c >> 3;
      int sboff = ((c & 7) * 16) ^ ((row & 7) << 4);
      gload_lds16(A + (size_t)(m0 + row) * K + k0 + (sboff >> 1), Ad + (size_t)c * 8);
    }
#pragma unroll
    for (int j = 0; j < 4; ++j) {
      int c = tid + j * 512;
      int row = c >> 3;
      int sboff = ((c & 7) * 16) ^ ((row & 7) << 4);
      gload_lds16(B + (size_t)(n0 + row) * K + k0 + (sboff >> 1), Bd + (size_t)c * 8);
    }
  };

  stage(0, 0);
  stage(1, 1);

  for (int t = 0; t < NT; ++t) {
    const int cur = t & 1;
    if (t + 1 < NT) { asm volatile("s_waitcnt vmcnt(8)" ::: "memory"); }
    else            { asm volatile("s_waitcnt vmcnt(0)" ::: "memory"); }
    __builtin_amdgcn_s_barrier();
    const char* Ab = (const char*)(lds + cur * 32768);
    const char* Bb = (const char*)(lds + cur * 32768 + 16384);
#pragma unroll
    for (int qm = 0; qm < 2; ++qm)
#pragma unroll
      for (int qn = 0; qn < 2; ++qn) {
        bf16x8 af[4][2], bfr[2][2];
#pragma unroll
        for (int mi = 0; mi < 4; ++mi) {
          int ra = wr * 128 + qm * 64 + mi * 16 + l16;
#pragma unroll
          for (int kk = 0; kk < 2; ++kk)
            af[mi][kk] = *(const bf16x8*)(Ab + ra * 128 + ((kk * 64 + lhi * 16) ^ ((ra & 7) << 4)));
        }
#pragma unroll
        for (int ni = 0; ni < 2; ++ni) {
          int rb = wc * 64 + qn * 32 + ni * 16 + l16;
#pragma unroll
          for (int kk = 0; kk < 2; ++kk)
            bfr[ni][kk] = *(const bf16x8*)(Bb + rb * 128 + ((kk * 64 + lhi * 16) ^ ((rb & 7) << 4)));
        }
        __builtin_amdgcn_s_setprio(1);
#pragma unroll
        for (int kk = 0; kk < 2; ++kk)
#pragma unroll
          for (int mi = 0; mi < 4; ++mi)
#pragma unroll
            for (int ni = 0; ni < 2; ++ni)
              acc[qm * 4 + mi][qn * 2 + ni] = __builtin_amdgcn_mfma_f32_16x16x32_bf16(
                  af[mi][kk], bfr[ni][kk], acc[qm * 4 + mi][qn * 2 + ni], 0, 0, 0);
        __builtin_amdgcn_s_setprio(0);
      }
    asm volatile("s_waitcnt lgkmcnt(0)" ::: "memory");
    __builtin_amdgcn_s_barrier();
    if (t + 2 < NT) stage(t + 2, cur);
  }

  if (EPI == 2) {
    float* o = (float*)outp;
#pragma unroll
    for (int mi8 = 0; mi8 < 8; ++mi8)
#pragma unroll
      for (int r = 0; r < 4; ++r) {
        int row = m0 + wr * 128 + mi8 * 16 + lhi * 4 + r;
#pragma unroll
        for (int nj = 0; nj < 4; ++nj) {
          int col = n0 + wc * 64 + nj * 16 + l16;
          o[(size_t)row * N + col] = acc[mi8][nj][r];
        }
      }
  } else {
    u16* o = (u16*)outp;
    const int nheads = N >> 7;
#pragma unroll
    for (int mi8 = 0; mi8 < 8; ++mi8)
#pragma unroll
      for (int r = 0; r < 4; ++r) {
        int row = m0 + wr * 128 + mi8 * 16 + lhi * 4 + r;
        int b = row >> 11;
        int tt = row & 2047;
#pragma unroll
        for (int nj = 0; nj < 4; ++nj) {
          int col = n0 + wc * 64 + nj * 16 + l16;
          int hh = col >> 7, dd = col & 127;
          float v = acc[mi8][nj][r];
          float p = __shfl_xor(v, 1);
          float c = cosp[tt * 64 + (dd >> 1)];
          float s = sinp[tt * 64 + (dd >> 1)];
          v = (lane & 1) ? fmaf(p, s, v * c) : fmaf(v, c, -p * s);
          v *= scale;
          o[((size_t)(b * nheads + hh) * 2048 + tt) * 128 + dd] = f2bf(v);
        }
      }
  }
}

// ---------------- 128x128 counted-vmcnt pipelined GEMM (KV projection) ----------------
// Same math body / EPI3 epilogue as the round-15 gemm_bt; pipeline upgraded to the
// proven gemm_bt256 pattern: 64KB LDS double-buffer (2 blocks/CU), vmcnt(8) counted
// waits (8 loads/thread/stage), raw barriers, setprio around the MFMA cluster.
__global__ __launch_bounds__(256, 2) void gemm_kv(const u16* __restrict__ A,
                                                  const u16* __restrict__ B,
                                                  u16* __restrict__ kp,
                                                  u16* __restrict__ vtp,
                                                  int M, int N, int K,
                                                  const float* __restrict__ cosp,
                                                  const float* __restrict__ sinp) {
  __shared__ u16 lds[32768];   // [buf][As 128x64 | Bs 128x64], 64KB
  const int tid = threadIdx.x;
  const int lane = tid & 63;
  const int l16 = lane & 15, lhi = lane >> 4;
  const int w = tid >> 6;
  const int wr = w >> 1, wc = w & 1;
  const int m0 = blockIdx.y * 128;
  const int n0 = blockIdx.x * 128;
  const int wbase = tid - lane;

  f32x4 acc[4][4];
#pragma unroll
  for (int i = 0; i < 4; ++i)
#pragma unroll
    for (int j = 0; j < 4; ++j) acc[i][j] = (f32x4)0.0f;

  const int NT = K >> 6;

  auto stage = [&](int t, int buf) {
    const int k0 = t << 6;
    u16* Ad = lds + buf * 16384;
    u16* Bd = Ad + 8192;
#pragma unroll
    for (int j = 0; j < 4; ++j) {
      int c = tid + j * 256;
      gload_lds16(A + (size_t)(m0 + (c >> 3)) * K + k0 + (c & 7) * 8,
                  Ad + (size_t)(wbase + j * 256) * 8);
    }
#pragma unroll
    for (int j = 0; j < 4; ++j) {
      int c = tid + j * 256;
      gload_lds16(B + (size_t)(n0 + (c >> 3)) * K + k0 + (c & 7) * 8,
                  Bd + (size_t)(wbase + j * 256) * 8);
    }
  };

  stage(0, 0);
  stage(1, 1);

  for (int t = 0; t < NT; ++t) {
    const int cur = t & 1;
    if (t + 1 < NT) { asm volatile("s_waitcnt vmcnt(8)" ::: "memory"); }
    else            { asm volatile("s_waitcnt vmcnt(0)" ::: "memory"); }
    __builtin_amdgcn_s_barrier();
    const u16* As = lds + cur * 16384;
    const u16* Bs = As + 8192;
#pragma unroll
    for (int kk = 0; kk < 64; kk += 32) {
      bf16x8 af[4], bfr[4];
#pragma unroll
      for (int mi = 0; mi < 4; ++mi)
        af[mi] = *(const bf16x8*)&As[(wr * 64 + mi * 16 + l16) * 64 + kk + lhi * 8];
#pragma unroll
      for (int ni = 0; ni < 4; ++ni)
        bfr[ni] = *(const bf16x8*)&Bs[(wc * 64 + ni * 16 + l16) * 64 + kk + lhi * 8];
      __builtin_amdgcn_s_setprio(1);
#pragma unroll
      for (int mi = 0; mi < 4; ++mi)
#pragma unroll
        for (int ni = 0; ni < 4; ++ni)
          acc[mi][ni] = __builtin_amdgcn_mfma_f32_16x16x32_bf16(af[mi], bfr[ni], acc[mi][ni], 0, 0, 0);
      __builtin_amdgcn_s_setprio(0);
    }
    asm volatile("s_waitcnt lgkmcnt(0)" ::: "memory");
    __builtin_amdgcn_s_barrier();
    if (t + 2 < NT) stage(t + 2, cur);
  }

  {  // merged KV epilogue
    const int bx = blockIdx.x;
    if (bx < 4) {   // K head bx: RoPE, (b, h=bx, t, d) layout
#pragma unroll
      for (int mi = 0; mi < 4; ++mi)
#pragma unroll
        for (int r = 0; r < 4; ++r) {
          int row = m0 + wr * 64 + mi * 16 + lhi * 4 + r;
          int b = row >> 11;
          int t = row & 2047;
          size_t base = ((size_t)(b * 4 + bx) * 2048 + t) * 128;
#pragma unroll
          for (int ni = 0; ni < 4; ++ni) {
            int d = wc * 64 + ni * 16 + l16;
            float v = acc[mi][ni][r];
            float p = __shfl_xor(v, 1);
            float c = cosp[t * 64 + (d >> 1)];
            float s = sinp[t * 64 + (d >> 1)];
            v = (lane & 1) ? fmaf(p, s, v * c) : fmaf(v, c, -p * s);
            kp[base + d] = f2bf(v);
          }
        }
    } else {        // V head (bx-4): write V^T (b, kvh, d, t)
      const int kvh = bx - 4;
#pragma unroll
      for (int mi = 0; mi < 4; ++mi)
#pragma unroll
        for (int r = 0; r < 4; ++r) {
          int row = m0 + wr * 64 + mi * 16 + lhi * 4 + r;
          int b = row >> 11;
          int t = row & 2047;
          size_t base = ((size_t)(b * 4 + kvh) * 128) * 2048 + t;
#pragma unroll
          for (int ni = 0; ni < 4; ++ni) {
            int d = wc * 64 + ni * 16 + l16;
            vtp[base + (size_t)d * 2048] = f2bf(acc[mi][ni][r]);
          }
        }
    }
  }
}

// ---------------- Flash attention: KVBLK=128, merged-sub softmax ----------------
// Grid 256 = 64 (h,b) x 4 pairs; block = 8 waves x 32 q-rows, paired q-tiles (pa, 7-pa).
// Per staged 128-kv tile: compute ALL FOUR QK^T chains (sub x kt2, independent -> 4-way
// MFMA ILP), then ONE softmax pass over 128 scores (one max tree, one defer/rescale,
// one exp+sum), then both PV blocks. Safety: guard t0 <= wrow0+31 implies t0 <= wrow0
// (t0-wrow0 = 0 mod 32), so kv=t0 is unmasked for every lane -> m always real -> fully
// masked sub1 rows exp to exactly 0 (same as the per-sub version).
__global__ __launch_bounds__(512, 2) void attn_kernel(const u16* __restrict__ Q,
                                                      const u16* __restrict__ Kp,
                                                      const u16* __restrict__ Vtp,
                                                      u16* __restrict__ O) {
  __shared__ u16 lds[65536];          // 128KB: buf b at b*32768 (K 16384 | V 16384 u16)

  const int tid = threadIdx.x;
  const int lane = tid & 63;
  const int w = tid >> 6;             // 0..7
  const int l5 = lane & 31, hi = lane >> 5;
  const int bid = blockIdx.x;
  const int hb = bid & 63;
  const int pa = bid >> 6;            // 0..3: q-tile pair (pa, 7-pa)
  const int h = hb >> 2;
  const int b = hb & 3;
  const int kvh = h >> 2;
  const int wbase = tid - lane;

  const u16* Kb = Kp + (size_t)(b * 4 + kvh) * 2048 * 128;
  const u16* Vtb = Vtp + (size_t)(b * 4 + kvh) * 128 * 2048;

  auto stageKV = [&](int kt, int buf) {
    const int t0k = kt * 128;
    u16* Kd = lds + buf * 32768;
    u16* Vd = Kd + 16384;
#pragma unroll
    for (int j = 0; j < 4; ++j) {
      int c = tid + j * 512;
      int row = c >> 4;                                  // 0..127
      int sboff = ((c & 15) * 16) ^ ((row & 15) << 4);   // byte in 256B row
      gload_lds16(Kb + (size_t)(t0k + row) * 128 + (sboff >> 1),
                  Kd + (size_t)(wbase + j * 512) * 8);
    }
#pragma unroll
    for (int j = 0; j < 4; ++j) {
      int c = tid + j * 512;
      int d = c >> 4;                                    // 0..127
      int sboff = ((c & 15) * 16) ^ ((d & 7) << 4);      // byte in 256B row
      gload_lds16(Vtb + (size_t)d * 2048 + t0k + (sboff >> 1),
                  Vd + (size_t)(wbase + j * 512) * 8);
    }
  };

  for (int pass = 0; pass < 2; ++pass) {
    const int qt = pass ? (7 - pa) : pa;
    const int q0 = qt * 256;
    const int wrow0 = q0 + w * 32;    // this wave's first q row
    const int qg = wrow0 + l5;        // this lane's q row

    const u16* Qb = Q + ((size_t)((b * 16 + h) * 2048 + wrow0)) * 128;
    bf16x8 qf[8];
#pragma unroll
    for (int ks = 0; ks < 8; ++ks)
      qf[ks] = *(const bf16x8*)(Qb + (size_t)l5 * 128 + ks * 16 + hi * 8);

    f32x16 oacc[4];
#pragma unroll
    for (int i = 0; i < 4; ++i) oacc[i] = (f32x16)0.0f;
    float m = -3.0e38f, l = 0.0f;

    const int nkt = 2 * qt + 2;       // 128-kv tiles
    stageKV(0, 0);

    for (int kt = 0; kt < nkt; ++kt) {
      const int t0 = kt * 128;
      const int cur = kt & 1;
      if (kt + 1 < nkt) {
        stageKV(kt + 1, cur ^ 1);
        asm volatile("s_waitcnt vmcnt(8)" ::: "memory");
      } else {
        asm volatile("s_waitcnt vmcnt(0)" ::: "memory");
      }
      __builtin_amdgcn_s_barrier();    // buf[cur] staged by all waves

      if (t0 <= wrow0 + 31) {          // wave-uniform guard for the 128-kv tile
        const char* vtb = (const char*)(lds + cur * 32768 + 16384);

        // All four QK^T chains (independent): p[sub][kt2*16+r] = S[kv][q],
        // kv = sub*64 + kt2*32 + (r&3)+8*(r>>2)+4*hi
        float p[2][32];
#pragma unroll
        for (int sub = 0; sub < 2; ++sub) {
          const char* ksb = (const char*)(lds + cur * 32768 + sub * 8192);
#pragma unroll
          for (int kt2 = 0; kt2 < 2; ++kt2) {
            f32x16 sacc = (f32x16)0.0f;
            int row = kt2 * 32 + l5;
            __builtin_amdgcn_s_setprio(1);
#pragma unroll
            for (int ks = 0; ks < 8; ++ks) {
              bf16x8 kf = *(const bf16x8*)(ksb + row * 256 + ((ks * 32 + hi * 16) ^ ((row & 15) << 4)));
              sacc = __builtin_amdgcn_mfma_f32_32x32x16_bf16(kf, qf[ks], sacc, 0, 0, 0);
            }
            __builtin_amdgcn_s_setprio(0);
#pragma unroll
            for (int r = 0; r < 16; ++r) p[sub][kt2 * 16 + r] = sacc[r];
          }
        }

        if (t0 + 127 > wrow0) {  // any part straddles/exceeds diagonal: causal mask
#pragma unroll
          for (int sub = 0; sub < 2; ++sub)
#pragma unroll
            for (int kt2 = 0; kt2 < 2; ++kt2)
#pragma unroll
              for (int r = 0; r < 16; ++r) {
                int kvg = t0 + sub * 64 + kt2 * 32 + (r & 3) + 8 * (r >> 2) + 4 * hi;
                if (kvg > qg) p[sub][kt2 * 16 + r] = -3.0e38f;
              }
        }

        // single in-lane row max over 128 + cross-half combine
        float mx[16];
#pragma unroll
        for (int i = 0; i < 16; ++i)
          mx[i] = fmaxf(fmaxf(p[0][i], p[0][i + 16]), fmaxf(p[1][i], p[1][i + 16]));
#pragma unroll
        for (int i = 0; i < 8; ++i) mx[i] = fmaxf(mx[i], mx[i + 8]);
#pragma unroll
        for (int i = 0; i < 4; ++i) mx[i] = fmaxf(mx[i], mx[i + 4]);
        float rm = fmaxf(fmaxf(mx[0], mx[1]), fmaxf(mx[2], mx[3]));
        rm = fmaxf(rm, __shfl_xor(rm, 32));

        bool defer = __all(rm <= m + 8.0f);
        if (!defer) {
          float mnew = fmaxf(m, rm);
          float sc = exp2f(m - mnew);
          m = mnew;
          l *= sc;
#pragma unroll
          for (int i = 0; i < 4; ++i)
#pragma unroll
            for (int r = 0; r < 16; ++r) oacc[i][r] *= sc;
        }

        // single exp + sum pass over 128
#pragma unroll
        for (int sub = 0; sub < 2; ++sub)
#pragma unroll
          for (int i = 0; i < 32; ++i) p[sub][i] = exp2f(p[sub][i] - m);
        float sm[16];
#pragma unroll
        for (int i = 0; i < 16; ++i)
          sm[i] = (p[0][i] + p[0][i + 16]) + (p[1][i] + p[1][i + 16]);
#pragma unroll
        for (int i = 0; i < 8; ++i) sm[i] += sm[i + 8];
#pragma unroll
        for (int i = 0; i < 4; ++i) sm[i] += sm[i + 4];
        float s2 = (sm[0] + sm[1]) + (sm[2] + sm[3]);
        s2 += __shfl_xor(s2, 32);
        l += s2;

        // P pack + permlane32_swap redistribute + PV (both subs)
#pragma unroll
        for (int sub = 0; sub < 2; ++sub) {
          const int vsub = sub * 128;  // byte col offset into V rows
#pragma unroll
          for (int kt2 = 0; kt2 < 2; ++kt2) {
#pragma unroll
            for (int sl = 0; sl < 2; ++sl) {
              int base = kt2 * 16 + sl * 8;
              unsigned A0 = cvtpk(p[sub][base + 0], p[sub][base + 1]);
              unsigned A1 = cvtpk(p[sub][base + 2], p[sub][base + 3]);
              unsigned A2 = cvtpk(p[sub][base + 4], p[sub][base + 5]);
              unsigned A3 = cvtpk(p[sub][base + 6], p[sub][base + 7]);
              asm volatile("v_permlane32_swap_b32 %0, %1" : "+v"(A0), "+v"(A2));
              asm volatile("v_permlane32_swap_b32 %0, %1" : "+v"(A1), "+v"(A3));
              union { unsigned u[4]; bf16x8 v; } pf;
              pf.u[0] = A0;
              pf.u[1] = A1;
              pf.u[2] = A2;
              pf.u[3] = A3;
              int s = kt2 * 2 + sl;
              __builtin_amdgcn_s_setprio(1);
#pragma unroll
              for (int dt = 0; dt < 4; ++dt) {
                int row = dt * 32 + l5;
                bf16x8 vb = *(const bf16x8*)(vtb + row * 256 + vsub +
                                             ((s * 32 + hi * 16) ^ ((row & 7) << 4)));
                oacc[dt] = __builtin_amdgcn_mfma_f32_32x32x16_bf16(vb, pf.v, oacc[dt], 0, 0, 0);
              }
              __builtin_amdgcn_s_setprio(0);
            }
          }
        }
      }

      asm volatile("s_waitcnt lgkmcnt(0)" ::: "memory");
      __builtin_amdgcn_s_barrier();    // all waves done reading buf[cur]
    }

    // normalize in-lane; two half-passes through OS overlay (waves 0-3, then 4-7)
    float inv = 1.0f / l;
    __syncthreads();
    for (int half = 0; half < 2; ++half) {
      if ((w >> 2) == half) {
        u16* OSw = lds + (w & 3) * 4352;     // [32 q][136] padded
#pragma unroll
        for (int dt = 0; dt < 4; ++dt)
#pragma unroll
          for (int r = 0; r < 16; ++r) {
            int d = dt * 32 + (r & 3) + 8 * (r >> 2) + 4 * hi;
            OSw[l5 * 136 + d] = f2bf(oacc[dt][r] * inv);
          }
      }
      __syncthreads();
      u16* Ob = O + ((size_t)(b * 2048 + q0 + half * 128)) * 2048 + h * 128;
#pragma unroll
      for (int j = 0; j < 4; ++j) {
        int c = tid + j * 512;
        int row = c >> 4, col = c & 15;
        *(bf16x8*)(Ob + (size_t)row * 2048 + col * 8) =
            *(const bf16x8*)&lds[(row >> 5) * 4352 + (row & 31) * 136 + col * 8];
      }
      __syncthreads();
    }
  }
}

extern "C" void kernel_launch(void* const* d_in, const int* in_sizes, int n_in,
                              void* d_out, int out_size, void* d_ws, size_t ws_size,
                              hipStream_t stream) {
  (void)in_sizes; (void)n_in; (void)out_size; (void)ws_size;
  const float* x    = (const float*)d_in[0];
  const float* Wq   = (const float*)d_in[1];
  const float* Wk   = (const float*)d_in[2];
  const float* Wv   = (const float*)d_in[3];
  const float* Wo   = (const float*)d_in[4];
  const float* cosp = (const float*)d_in[5];
  const float* sinp = (const float*)d_in[6];

  u16* ws  = (u16*)d_ws;
  u16* xbf = ws;               // 16,777,216 elems (B*T x C)  -- reused as attn out
  u16* Wqb = xbf + 16777216;   //  4,194,304
  u16* Wkb = Wqb + 4194304;    //  1,048,576  } contiguous 1024x2048 KV weight
  u16* Wvb = Wkb + 1048576;    //  1,048,576  }
  u16* Wob = Wvb + 1048576;    //  4,194,304
  u16* Qb  = Wob + 4194304;    // 16,777,216 (B,H,T,D)
  u16* Kb  = Qb + 16777216;    //  4,194,304 (B,HKV,T,D)
  u16* Vb  = Kb + 4194304;     //  4,194,304 (B,HKV,D,T)  == V^T
  u16* AO  = xbf;              // attention output (B,T,C), reuses x region

  cast_all_kernel<<<2048, 256, 0, stream>>>(x, Wq, Wk, Wv, Wo, ws);

  const float qscale = (float)(1.4426950408889634 / sqrt(128.0));

  gemm_bt256<0><<<dim3(8, 32), 512, 0, stream>>>(xbf, Wqb, Qb, 8192, 2048, 2048, cosp, sinp, qscale);
  gemm_kv<<<dim3(8, 64), 256, 0, stream>>>(xbf, Wkb, Kb, Vb, 8192, 1024, 2048, cosp, sinp);

  attn_kernel<<<256, 512, 0, stream>>>(Qb, Kb, Vb, AO);

  gemm_bt256<2><<<dim3(8, 32), 512, 0, stream>>>(AO, Wob, d_out, 8192, 2048, 2048, nullptr, nullptr, 1.0f);
}